// Round 6
// baseline (229.573 us; speedup 1.0000x reference)
//
#include <hip/hip_runtime.h>

typedef __attribute__((ext_vector_type(8))) short s16x8;
typedef __attribute__((ext_vector_type(4))) float f32x4;

#define BB   512
#define LL   2048
#define DD   128
#define HH   128
#define SUB  128              // leaves per subtree (R4 shape)
#define NSUB (LL / SUB)       // 16 subtrees per sample
#define NBLK (BB * NSUB)      // 8192 subtrees total
#define GRID 768              // persistent blocks: 3 per CU, all co-resident
#define K1ROWS 8              // rows k1 leaves per subtree (4 comp levels)
#define K2ROWS (NSUB * K1ROWS)  // 128 rows per sample into k2 (16 MB ws)

// f32 -> bf16 bits, RNE
__device__ __forceinline__ short f2bf(float x) {
  unsigned u = __builtin_bit_cast(unsigned, x);
  u += 0x7fffu + ((u >> 16) & 1u);
  return (short)(u >> 16);
}
// packed f32x2 -> bf16x2 (gfx950 v_cvt_pk_bf16_f32, RNE)
__device__ __forceinline__ unsigned pk_bf16(float a, float b) {
  unsigned r;
  asm("v_cvt_pk_bf16_f32 %0, %1, %2" : "=v"(r) : "v"(a), "v"(b));
  return r;
}
// tanh via exp; valid-row preacts norm-bounded; garbage rows write-masked
__device__ __forceinline__ float tanh_fast(float x) {
  float e2 = __expf(2.f * x);
  return (e2 - 1.f) * __builtin_amdgcn_rcpf(e2 + 1.f);
}

// LDS byte address for [row][inner(bytes)] in a [*][256B] bf16 tile; XOR
// swizzle breaks the 256B-row-stride bank alignment for strided ds_read_b128.
__device__ __forceinline__ int swz(int row, int inner) {
  return row * 256 + (inner ^ (((row >> 1) & 7) << 4));
}

// ---- prep: W_in^T, W_comp^T as bf16 ----
__global__ __launch_bounds__(256) void k_prep(
    const float* __restrict__ Win, const float* __restrict__ Wcomp,
    short* __restrict__ WiT, short* __restrict__ WcT) {
  const int i0 = blockIdx.x * 256 + threadIdx.x;
  const int stride = gridDim.x * 256;
  for (int idx = i0; idx < 128 * 128; idx += stride) {
    int n = idx >> 7, k = idx & 127;
    WiT[idx] = f2bf(Win[k * 128 + n]);     // WiT[n][k]
  }
  for (int idx = i0; idx < 128 * 256; idx += stride) {
    int n = idx >> 8, k = idx & 255;
    WcT[idx] = f2bf(Wcomp[k * 128 + n]);   // WcT[n][k]
  }
}

// One 16-row tree M-tile: A row i = concat(src[2*(mt_in*16+i)], src[...+1]),
// K=256 against wfc.
__device__ __forceinline__ void tree_mm(const short* src, int mt_in,
                                        const s16x8 (&wfc)[8][2], int lm,
                                        int lh, f32x4& c0, f32x4& c1) {
  s16x8 a[8];
#pragma unroll
  for (int kt = 0; kt < 8; ++kt) {
    int k = kt * 32 + lh * 8;
    int rowbuf = 2 * (mt_in * 16 + lm) + (k >> 7);
    a[kt] = *(const s16x8*)((const char*)src + swz(rowbuf, (k & 127) * 2));
  }
  c0 = (f32x4){0.f, 0.f, 0.f, 0.f};
  c1 = (f32x4){0.f, 0.f, 0.f, 0.f};
#pragma unroll
  for (int kt = 0; kt < 8; ++kt) {
    c0 = __builtin_amdgcn_mfma_f32_16x16x32_bf16(a[kt], wfc[kt][0], c0, 0, 0, 0);
    c1 = __builtin_amdgcn_mfma_f32_16x16x32_bf16(a[kt], wfc[kt][1], c1, 0, 0, 0);
  }
}

__device__ __forceinline__ void h0_tile(const short* ldsE, short* ldsB,
                                        int mtl, int mtg,
                                        const s16x8 (&wfin)[4][2], float bi0,
                                        float bi1, int lm, int lh, int col0) {
  s16x8 a[4];
#pragma unroll
  for (int kt = 0; kt < 4; ++kt)
    a[kt] = *(const s16x8*)((const char*)ldsE +
                            swz(mtl * 16 + lm, kt * 64 + lh * 16));
  f32x4 c0 = {0.f, 0.f, 0.f, 0.f}, c1 = {0.f, 0.f, 0.f, 0.f};
#pragma unroll
  for (int kt = 0; kt < 4; ++kt) {
    c0 = __builtin_amdgcn_mfma_f32_16x16x32_bf16(a[kt], wfin[kt][0], c0, 0, 0, 0);
    c1 = __builtin_amdgcn_mfma_f32_16x16x32_bf16(a[kt], wfin[kt][1], c1, 0, 0, 0);
  }
#pragma unroll
  for (int r = 0; r < 4; ++r) {
    int row = mtg * 16 + lh * 4 + r;
    *(unsigned*)((char*)ldsB + swz(row, col0 * 2)) =
        pk_bf16(c0[r] + bi0, c1[r] + bi1);  // no tanh at level 0
  }
}

// Persistent: each block loops over subtrees s = blk, blk+GRID, ...
// W_comp fragments loaded ONCE; next-subtree ids + E-chunk0 prefetched into
// registers during the current subtree's tree levels.
__global__ __launch_bounds__(256, 3) void k_subtree(
    const int* __restrict__ ids, const float* __restrict__ emb,
    const short* __restrict__ WiT, const float* __restrict__ bin,
    const short* __restrict__ WcT, const float* __restrict__ bcomp,
    short* __restrict__ wsbf) {
  __shared__ __align__(16) short ldsE[64 * 128];   // 16 KB (E chunk / tree ping)
  __shared__ __align__(16) short ldsB[128 * 128];  // 32 KB
  const int tid = threadIdx.x;
  const int wave = tid >> 6, lane = tid & 63;
  const int lh = lane >> 4, lm = lane & 15;
  const int n0 = wave * 32;
  const int col0 = n0 + 2 * lm;  // lane owns cols col0, col0+1
  const int gr = tid >> 5;       // gather row-within-8 (0..7)
  const int gc = tid & 31;       // gather col (float4 index)

  // persistent W_comp fragments + biases
  s16x8 wfc[8][2];
#pragma unroll
  for (int kt = 0; kt < 8; ++kt)
#pragma unroll
    for (int nt = 0; nt < 2; ++nt)
      wfc[kt][nt] = *(const s16x8*)(WcT + (col0 + nt) * 256 + kt * 32 + lh * 8);
  const float2 biv = *(const float2*)(bin + col0);
  const float2 bcv = *(const float2*)(bcomp + col0);

  // ---- prologue prefetch for first subtree ----
  int idv[16];
#pragma unroll
  for (int it = 0; it < 16; ++it)
    idv[it] = ids[(long)blockIdx.x * SUB + it * 8 + gr];
  uint2 gp0[8];
#pragma unroll
  for (int j = 0; j < 8; ++j) {
    const float4 v = ((const float4*)(emb + (long)idv[j] * DD))[gc];
    gp0[j].x = pk_bf16(v.x, v.y);
    gp0[j].y = pk_bf16(v.z, v.w);
  }

#pragma unroll 1
  for (int s = blockIdx.x; s < NBLK; s += GRID) {
    // write prefetched chunk0 -> ldsE; issue wfin loads (used after bar)
#pragma unroll
    for (int j = 0; j < 8; ++j)
      *(uint2*)((char*)ldsE + swz(j * 8 + gr, gc * 8)) = gp0[j];
    s16x8 wfin[4][2];
#pragma unroll
    for (int kt = 0; kt < 4; ++kt)
#pragma unroll
      for (int nt = 0; nt < 2; ++nt)
        wfin[kt][nt] =
            *(const s16x8*)(WiT + (col0 + nt) * 128 + kt * 32 + lh * 8);
    __syncthreads();

    // issue chunk1 loads (rows 64-127, this subtree); latency under h0c0
    float4 g1[8];
#pragma unroll
    for (int j = 0; j < 8; ++j)
      g1[j] = ((const float4*)(emb + (long)idv[8 + j] * DD))[gc];

    // h0 chunk0: E rows 0-63 -> ldsB rows 0-63
#pragma unroll 1
    for (int mtl = 0; mtl < 4; ++mtl)
      h0_tile(ldsE, ldsB, mtl, mtl, wfin, biv.x, biv.y, lm, lh, col0);
    __syncthreads();  // all waves done reading ldsE

    // write chunk1 -> ldsE; issue next-subtree id loads
#pragma unroll
    for (int j = 0; j < 8; ++j) {
      uint2 pv;
      pv.x = pk_bf16(g1[j].x, g1[j].y);
      pv.y = pk_bf16(g1[j].z, g1[j].w);
      *(uint2*)((char*)ldsE + swz(j * 8 + gr, gc * 8)) = pv;
    }
    {
      int sn = s + GRID;
      if (sn >= NBLK) sn = 0;  // harmless wrap (prefetch unused at exit)
#pragma unroll
      for (int it = 0; it < 16; ++it)
        idv[it] = ids[(long)sn * SUB + it * 8 + gr];
    }
    __syncthreads();

    // h0 chunk1: -> ldsB rows 64-127
#pragma unroll 1
    for (int mtl = 0; mtl < 4; ++mtl)
      h0_tile(ldsE, ldsB, mtl, 4 + mtl, wfin, biv.x, biv.y, lm, lh, col0);

    // issue next-subtree chunk0 loads (rows 0-63); pack after lev0
    float4 gn[8];
#pragma unroll
    for (int j = 0; j < 8; ++j)
      gn[j] = ((const float4*)(emb + (long)idv[j] * DD))[gc];
    __syncthreads();

    // lev0: ldsB(128 rows) -> ldsE(64 rows)
#pragma unroll 1
    for (int mt = 0; mt < 4; ++mt) {
      f32x4 c0, c1;
      tree_mm(ldsB, mt, wfc, lm, lh, c0, c1);
#pragma unroll
      for (int r = 0; r < 4; ++r) {
        int row = mt * 16 + lh * 4 + r;
        *(unsigned*)((char*)ldsE + swz(row, col0 * 2)) =
            pk_bf16(tanh_fast(c0[r] + bcv.x), tanh_fast(c1[r] + bcv.y));
      }
    }
    // pack next chunk0 (loads returned during lev0)
#pragma unroll
    for (int j = 0; j < 8; ++j) {
      gp0[j].x = pk_bf16(gn[j].x, gn[j].y);
      gp0[j].y = pk_bf16(gn[j].z, gn[j].w);
    }
    __syncthreads();

    // lev1: ldsE(64) -> ldsB(32)
#pragma unroll 1
    for (int mt = 0; mt < 2; ++mt) {
      f32x4 c0, c1;
      tree_mm(ldsE, mt, wfc, lm, lh, c0, c1);
#pragma unroll
      for (int r = 0; r < 4; ++r) {
        int row = mt * 16 + lh * 4 + r;
        *(unsigned*)((char*)ldsB + swz(row, col0 * 2)) =
            pk_bf16(tanh_fast(c0[r] + bcv.x), tanh_fast(c1[r] + bcv.y));
      }
    }
    __syncthreads();

    // lev2: ldsB(32) -> ldsE(16 rows, all valid level-3 rows)
    {
      f32x4 c0, c1;
      tree_mm(ldsB, 0, wfc, lm, lh, c0, c1);
#pragma unroll
      for (int r = 0; r < 4; ++r) {
        int row = lh * 4 + r;
        *(unsigned*)((char*)ldsE + swz(row, col0 * 2)) =
            pk_bf16(tanh_fast(c0[r] + bcv.x), tanh_fast(c1[r] + bcv.y));
      }
    }
    __syncthreads();

    // lev3: ldsE(16 valid; 16-31 stale-but-finite lev0) -> global, 8 rows
    {
      f32x4 c0, c1;
      tree_mm(ldsE, 0, wfc, lm, lh, c0, c1);
#pragma unroll
      for (int r = 0; r < 4; ++r) {
        int row = lh * 4 + r;
        if (row < K1ROWS)
          *(unsigned*)(wsbf + ((long)s * K1ROWS + row) * HH + col0) =
              pk_bf16(tanh_fast(c0[r] + bcv.x), tanh_fast(c1[r] + bcv.y));
      }
    }
    __syncthreads();  // ldsE free before next iteration's gp0 write
  }
}

// ---- k2: per-sample 128 rows -> root -> classifier (MFMA) ----
__global__ __launch_bounds__(256, 2) void k_tree2(
    const short* __restrict__ wsbf, const short* __restrict__ WcT,
    const float* __restrict__ bcomp, const float* __restrict__ Wcls,
    const float* __restrict__ bcls, float* __restrict__ out) {
  __shared__ __align__(16) short srcL[128 * 128];  // 32 KB
  __shared__ __align__(16) short dstS[64 * 128];   // 16 KB
  __shared__ float rootL[128];
  const int b = blockIdx.x, tid = threadIdx.x;
  const int wave = tid >> 6, lane = tid & 63;
  const int lh = lane >> 4, lm = lane & 15;
  const int n0 = wave * 32;
  const int col0 = n0 + 2 * lm;

  s16x8 wfc[8][2];
#pragma unroll
  for (int kt = 0; kt < 8; ++kt)
#pragma unroll
    for (int nt = 0; nt < 2; ++nt)
      wfc[kt][nt] = *(const s16x8*)(WcT + (col0 + nt) * 256 + kt * 32 + lh * 8);
  const float2 bcv = *(const float2*)(bcomp + col0);

  // load 128 rows of bf16 (16 B per lane, coalesced) -> srcL swizzled
#pragma unroll
  for (int it = 0; it < 8; ++it) {
    int row = it * 16 + (tid >> 4);
    s16x8 v = *(const s16x8*)(wsbf + ((long)b * K2ROWS + row) * HH + (tid & 15) * 8);
    *(s16x8*)((char*)srcL + swz(row, (tid & 15) * 16)) = v;
  }
  __syncthreads();

  const short* src = srcL;
  short* dst = dstS;
  // levels: 128->64->32->16->8->4->2->1 ; mtiles 4,2,1,1,1,1,1
  const int mtiles[7] = {4, 2, 1, 1, 1, 1, 1};
  const int rlim[7] = {64, 32, 16, 8, 4, 2, 1};
#pragma unroll 1
  for (int lev = 0; lev < 7; ++lev) {
    int nmt = mtiles[lev], rl = rlim[lev];
#pragma unroll 1
    for (int mt = 0; mt < nmt; ++mt) {
      f32x4 c0, c1;
      tree_mm(src, mt, wfc, lm, lh, c0, c1);
      if (lev == 6) {
        if (lh == 0) {
          rootL[col0] = tanh_fast(c0[0] + bcv.x);
          rootL[col0 + 1] = tanh_fast(c1[0] + bcv.y);
        }
      } else {
#pragma unroll
        for (int r = 0; r < 4; ++r) {
          int row = mt * 16 + lh * 4 + r;
          if (row < rl)
            *(unsigned*)((char*)dst + swz(row, col0 * 2)) =
                pk_bf16(tanh_fast(c0[r] + bcv.x), tanh_fast(c1[r] + bcv.y));
        }
      }
    }
    __syncthreads();
    const short* t = src;
    src = dst;
    dst = (short*)t;
  }

  // classifier: wave 0; lane -> (class = lane&1, k-chunk = lane>>1)
  if (wave == 0) {
    int c = lane & 1, kb = lane >> 1;
    float p = 0.f;
#pragma unroll
    for (int j = 0; j < 4; ++j) {
      int k = kb + 32 * j;
      p += rootL[k] * Wcls[k * 2 + c];
    }
#pragma unroll
    for (int m = 2; m <= 32; m <<= 1) p += __shfl_xor(p, m, 64);
    if (lane < 2) out[b * 2 + lane] = p + bcls[lane];
  }
}

extern "C" void kernel_launch(void* const* d_in, const int* in_sizes, int n_in,
                              void* d_out, int out_size, void* d_ws, size_t ws_size,
                              hipStream_t stream) {
  const int*   ids   = (const int*)d_in[0];
  const float* emb   = (const float*)d_in[1];
  const float* Win   = (const float*)d_in[2];
  const float* bin   = (const float*)d_in[3];
  const float* Wcomp = (const float*)d_in[4];
  const float* bcomp = (const float*)d_in[5];
  const float* Wcls  = (const float*)d_in[6];
  const float* bcls  = (const float*)d_in[7];
  char* wsb = (char*)d_ws;
  short* wsbf = (short*)wsb;                            // 16 MB bf16 k1->k2 rows
  const size_t WSBF_BYTES = (size_t)BB * NSUB * K1ROWS * HH * 2;  // 16 MB
  short* WcT = (short*)(wsb + WSBF_BYTES);              // 64 KB
  short* WiT = (short*)(wsb + WSBF_BYTES + 65536);      // 32 KB
  float* out = (float*)d_out;

  hipLaunchKernelGGL(k_prep, dim3(64), dim3(256), 0, stream, Win, Wcomp, WiT, WcT);
  hipLaunchKernelGGL(k_subtree, dim3(GRID), dim3(256), 0, stream,
                     ids, emb, WiT, bin, WcT, bcomp, wsbf);
  hipLaunchKernelGGL(k_tree2, dim3(BB), dim3(256), 0, stream,
                     wsbf, WcT, bcomp, Wcls, bcls, out);
}

// Round 7
// 181.524 us; speedup vs baseline: 1.2647x; 1.2647x over previous
//
#include <hip/hip_runtime.h>

typedef __attribute__((ext_vector_type(8))) short s16x8;
typedef __attribute__((ext_vector_type(4))) float f32x4;

#define BB   512
#define LL   2048
#define DD   128
#define HH   128
#define SUB  128              // leaves per subtree
#define NSUB (LL / SUB)       // 16 subtrees per sample
#define NBLK (BB * NSUB)      // 8192 subtrees
#define K1ROWS 8              // rows k1 leaves per subtree (lev0'..lev3)
#define K2ROWS (NSUB * K1ROWS)  // 128 rows per sample into k2 (16 MB ws)

// f32 -> bf16 bits, RNE
__device__ __forceinline__ short f2bf(float x) {
  unsigned u = __builtin_bit_cast(unsigned, x);
  u += 0x7fffu + ((u >> 16) & 1u);
  return (short)(u >> 16);
}
// packed f32x2 -> bf16x2 (gfx950 v_cvt_pk_bf16_f32, RNE)
__device__ __forceinline__ unsigned pk_bf16(float a, float b) {
  unsigned r;
  asm("v_cvt_pk_bf16_f32 %0, %1, %2" : "=v"(r) : "v"(a), "v"(b));
  return r;
}
// tanh via exp; valid-row preacts norm-bounded; garbage rows write-masked
__device__ __forceinline__ float tanh_fast(float x) {
  float e2 = __expf(2.f * x);
  return (e2 - 1.f) * __builtin_amdgcn_rcpf(e2 + 1.f);
}

// LDS byte address for [row][inner(bytes)] in a [*][256B] bf16 tile; XOR
// swizzle breaks the 256B-row-stride bank alignment for strided ds_read_b128.
__device__ __forceinline__ int swz(int row, int inner) {
  return row * 256 + (inner ^ (((row >> 1) & 7) << 4));
}

// ---- prep (one launch, 161 blocks):
//  b<128   : WmT[n][k] = (k<128 ? (Win@Wc_top)[k][n] : (Win@Wc_bot)[k-128][n])
//  b in [128,160): WcT[n][k] = Wcomp[k][n] bf16
//  b==160  : b1[n] = bin@(Wc_top+Wc_bot)[:,n] + bcomp[n]  (fp32)
__global__ __launch_bounds__(256) void k_prep(
    const float* __restrict__ Win, const float* __restrict__ Wcomp,
    const float* __restrict__ bin, const float* __restrict__ bcomp,
    short* __restrict__ WmT, short* __restrict__ WcT,
    float* __restrict__ b1f) {
  const int b = blockIdx.x, t = threadIdx.x;
  if (b < 128) {
    const int d = b;            // k-index of the folded E-dot
    const int half = t >> 7, n = t & 127;
    float acc = 0.f;
    for (int k = 0; k < 128; ++k)
      acc += Win[d * 128 + k] * Wcomp[(k + 128 * half) * 128 + n];
    WmT[n * 256 + half * 128 + d] = f2bf(acc);
  } else if (b < 160) {
    for (int idx = (b - 128) * 256 + t; idx < 128 * 256; idx += 32 * 256) {
      int n = idx >> 8, k = idx & 255;
      WcT[idx] = f2bf(Wcomp[k * 128 + n]);
    }
  } else {
    if (t < 128) {
      float acc = bcomp[t];
      for (int k = 0; k < 128; ++k)
        acc += bin[k] * (Wcomp[k * 128 + t] + Wcomp[(k + 128) * 128 + t]);
      b1f[t] = acc;
    }
  }
}

// One 16-row tree M-tile: A row i = concat(src[2*(mt_in*16+i)], src[...+1]),
// K=256 against the given B-fragments.
__device__ __forceinline__ void tree_mm(const short* src, int mt_in,
                                        const s16x8 (&wf)[8][2], int lm,
                                        int lh, f32x4& c0, f32x4& c1) {
  s16x8 a[8];
#pragma unroll
  for (int kt = 0; kt < 8; ++kt) {
    int k = kt * 32 + lh * 8;
    int rowbuf = 2 * (mt_in * 16 + lm) + (k >> 7);
    a[kt] = *(const s16x8*)((const char*)src + swz(rowbuf, (k & 127) * 2));
  }
  c0 = (f32x4){0.f, 0.f, 0.f, 0.f};
  c1 = (f32x4){0.f, 0.f, 0.f, 0.f};
#pragma unroll
  for (int kt = 0; kt < 8; ++kt) {
    c0 = __builtin_amdgcn_mfma_f32_16x16x32_bf16(a[kt], wf[kt][0], c0, 0, 0, 0);
    c1 = __builtin_amdgcn_mfma_f32_16x16x32_bf16(a[kt], wf[kt][1], c1, 0, 0, 0);
  }
}

// k1: gather 128 E rows -> lev0' (folded W_in·W_comp) -> lev1..lev3 -> ws
__global__ __launch_bounds__(256, 3) void k_subtree(
    const int* __restrict__ ids, const float* __restrict__ emb,
    const short* __restrict__ WmT, const short* __restrict__ WcT,
    const float* __restrict__ b1f, const float* __restrict__ bcomp,
    short* __restrict__ wsbf) {
  __shared__ __align__(16) short ldsB[128 * 128];  // 32 KB: E pairs / pong
  __shared__ __align__(16) short ldsE[64 * 128];   // 16 KB: ping
  const int blk = blockIdx.x, tid = threadIdx.x;
  const int wave = tid >> 6, lane = tid & 63;
  const int lh = lane >> 4, lm = lane & 15;
  const int n0 = wave * 32;
  const int col0 = n0 + 2 * lm;  // lane owns cols col0, col0+1

  // leaf ids
  int idv[16];
#pragma unroll
  for (int it = 0; it < 16; ++it)
    idv[it] = ids[(long)blk * SUB + it * 8 + (tid >> 5)];

  // weight B-fragments: folded M (lev0') and W_comp (lev1+)
  s16x8 wfm[8][2], wfc[8][2];
#pragma unroll
  for (int kt = 0; kt < 8; ++kt)
#pragma unroll
    for (int nt = 0; nt < 2; ++nt) {
      wfm[kt][nt] = *(const s16x8*)(WmT + (col0 + nt) * 256 + kt * 32 + lh * 8);
      wfc[kt][nt] = *(const s16x8*)(WcT + (col0 + nt) * 256 + kt * 32 + lh * 8);
    }
  const float2 b1v = *(const float2*)(b1f + col0);
  const float2 bcv = *(const float2*)(bcomp + col0);

  // gather all 128 E rows -> ldsB (bf16, swizzled), single phase
#pragma unroll
  for (int it = 0; it < 16; ++it) {
    int r = it * 8 + (tid >> 5);
    const float4 v = ((const float4*)(emb + (long)idv[it] * DD))[tid & 31];
    uint2 pv;
    pv.x = pk_bf16(v.x, v.y);
    pv.y = pk_bf16(v.z, v.w);
    *(uint2*)((char*)ldsB + swz(r, (tid & 31) * 8)) = pv;
  }
  __syncthreads();

  // lev0': E pairs (128 rows) x M -> ldsE rows 0-63 (tanh, folded bias)
#pragma unroll 1
  for (int mt = 0; mt < 4; ++mt) {
    f32x4 c0, c1;
    tree_mm(ldsB, mt, wfm, lm, lh, c0, c1);
#pragma unroll
    for (int r = 0; r < 4; ++r) {
      int row = mt * 16 + lh * 4 + r;
      *(unsigned*)((char*)ldsE + swz(row, col0 * 2)) =
          pk_bf16(tanh_fast(c0[r] + b1v.x), tanh_fast(c1[r] + b1v.y));
    }
  }
  __syncthreads();

  // lev1: ldsE(64) -> ldsB rows 0-31
#pragma unroll 1
  for (int mt = 0; mt < 2; ++mt) {
    f32x4 c0, c1;
    tree_mm(ldsE, mt, wfc, lm, lh, c0, c1);
#pragma unroll
    for (int r = 0; r < 4; ++r) {
      int row = mt * 16 + lh * 4 + r;
      *(unsigned*)((char*)ldsB + swz(row, col0 * 2)) =
          pk_bf16(tanh_fast(c0[r] + bcv.x), tanh_fast(c1[r] + bcv.y));
    }
  }
  __syncthreads();

  // lev2: ldsB(32) -> ldsE rows 0-15 (all valid)
  {
    f32x4 c0, c1;
    tree_mm(ldsB, 0, wfc, lm, lh, c0, c1);
#pragma unroll
    for (int r = 0; r < 4; ++r) {
      int row = lh * 4 + r;
      *(unsigned*)((char*)ldsE + swz(row, col0 * 2)) =
          pk_bf16(tanh_fast(c0[r] + bcv.x), tanh_fast(c1[r] + bcv.y));
    }
  }
  __syncthreads();

  // lev3: ldsE rows 0-15 valid (16-31 stale lev0', finite) -> global, 8 rows
  // D rows 0-7 use A pair-rows 0-15 (valid only); garbage reaches rows >=8.
  {
    f32x4 c0, c1;
    tree_mm(ldsE, 0, wfc, lm, lh, c0, c1);
#pragma unroll
    for (int r = 0; r < 4; ++r) {
      int row = lh * 4 + r;
      if (row < K1ROWS)
        *(unsigned*)(wsbf + ((long)blk * K1ROWS + row) * HH + col0) =
            pk_bf16(tanh_fast(c0[r] + bcv.x), tanh_fast(c1[r] + bcv.y));
    }
  }
}

// ---- k2: per-sample 128 rows -> root -> classifier (MFMA) ----
__global__ __launch_bounds__(256, 2) void k_tree2(
    const short* __restrict__ wsbf, const short* __restrict__ WcT,
    const float* __restrict__ bcomp, const float* __restrict__ Wcls,
    const float* __restrict__ bcls, float* __restrict__ out) {
  __shared__ __align__(16) short srcL[128 * 128];  // 32 KB
  __shared__ __align__(16) short dstS[64 * 128];   // 16 KB
  __shared__ float rootL[128];
  const int b = blockIdx.x, tid = threadIdx.x;
  const int wave = tid >> 6, lane = tid & 63;
  const int lh = lane >> 4, lm = lane & 15;
  const int n0 = wave * 32;
  const int col0 = n0 + 2 * lm;

  s16x8 wfc[8][2];
#pragma unroll
  for (int kt = 0; kt < 8; ++kt)
#pragma unroll
    for (int nt = 0; nt < 2; ++nt)
      wfc[kt][nt] = *(const s16x8*)(WcT + (col0 + nt) * 256 + kt * 32 + lh * 8);
  const float2 bcv = *(const float2*)(bcomp + col0);

  // load 128 rows of bf16 (16 B per lane, coalesced) -> srcL swizzled
#pragma unroll
  for (int it = 0; it < 8; ++it) {
    int row = it * 16 + (tid >> 4);
    s16x8 v = *(const s16x8*)(wsbf + ((long)b * K2ROWS + row) * HH + (tid & 15) * 8);
    *(s16x8*)((char*)srcL + swz(row, (tid & 15) * 16)) = v;
  }
  __syncthreads();

  const short* src = srcL;
  short* dst = dstS;
  // levels: 128->64->32->16->8->4->2->1 ; mtiles 4,2,1,1,1,1,1
  const int mtiles[7] = {4, 2, 1, 1, 1, 1, 1};
  const int rlim[7] = {64, 32, 16, 8, 4, 2, 1};
#pragma unroll 1
  for (int lev = 0; lev < 7; ++lev) {
    int nmt = mtiles[lev], rl = rlim[lev];
#pragma unroll 1
    for (int mt = 0; mt < nmt; ++mt) {
      f32x4 c0, c1;
      tree_mm(src, mt, wfc, lm, lh, c0, c1);
      if (lev == 6) {
        if (lh == 0) {
          rootL[col0] = tanh_fast(c0[0] + bcv.x);
          rootL[col0 + 1] = tanh_fast(c1[0] + bcv.y);
        }
      } else {
#pragma unroll
        for (int r = 0; r < 4; ++r) {
          int row = mt * 16 + lh * 4 + r;
          if (row < rl)
            *(unsigned*)((char*)dst + swz(row, col0 * 2)) =
                pk_bf16(tanh_fast(c0[r] + bcv.x), tanh_fast(c1[r] + bcv.y));
        }
      }
    }
    __syncthreads();
    const short* t = src;
    src = dst;
    dst = (short*)t;
  }

  // classifier: wave 0; lane -> (class = lane&1, k-chunk = lane>>1)
  if (wave == 0) {
    int c = lane & 1, kb = lane >> 1;
    float p = 0.f;
#pragma unroll
    for (int j = 0; j < 4; ++j) {
      int k = kb + 32 * j;
      p += rootL[k] * Wcls[k * 2 + c];
    }
#pragma unroll
    for (int m = 2; m <= 32; m <<= 1) p += __shfl_xor(p, m, 64);
    if (lane < 2) out[b * 2 + lane] = p + bcls[lane];
  }
}

extern "C" void kernel_launch(void* const* d_in, const int* in_sizes, int n_in,
                              void* d_out, int out_size, void* d_ws, size_t ws_size,
                              hipStream_t stream) {
  const int*   ids   = (const int*)d_in[0];
  const float* emb   = (const float*)d_in[1];
  const float* Win   = (const float*)d_in[2];
  const float* bin   = (const float*)d_in[3];
  const float* Wcomp = (const float*)d_in[4];
  const float* bcomp = (const float*)d_in[5];
  const float* Wcls  = (const float*)d_in[6];
  const float* bcls  = (const float*)d_in[7];
  char* wsb = (char*)d_ws;
  // layout: [wsbf 16 MB][WcT 64 KB][WmT 128 KB][b1 512 B]
  short* wsbf = (short*)wsb;
  const size_t WSBF_BYTES = (size_t)BB * NSUB * K1ROWS * HH * 2;  // 16 MB
  short* WcT = (short*)(wsb + WSBF_BYTES);
  short* WmT = (short*)(wsb + WSBF_BYTES + (64 << 10));
  float* b1f = (float*)(wsb + WSBF_BYTES + (192 << 10));
  float* out = (float*)d_out;

  hipLaunchKernelGGL(k_prep, dim3(161), dim3(256), 0, stream,
                     Win, Wcomp, bin, bcomp, WmT, WcT, b1f);
  hipLaunchKernelGGL(k_subtree, dim3(NBLK), dim3(256), 0, stream,
                     ids, emb, WmT, WcT, b1f, bcomp, wsbf);
  hipLaunchKernelGGL(k_tree2, dim3(BB), dim3(256), 0, stream,
                     wsbf, WcT, bcomp, Wcls, bcls, out);
}

// Round 8
// 175.685 us; speedup vs baseline: 1.3067x; 1.0332x over previous
//
#include <hip/hip_runtime.h>

typedef __attribute__((ext_vector_type(8))) short s16x8;
typedef __attribute__((ext_vector_type(4))) float f32x4;

#define BB   512
#define LL   2048
#define DD   128
#define HH   128
#define SUB  128              // leaves per subtree
#define NSUB (LL / SUB)       // 16 subtrees per sample
#define NBLK (BB * NSUB)      // 8192 subtrees
#define K1ROWS 8              // rows k1 leaves per subtree (lev0'..lev3)
#define K2ROWS (NSUB * K1ROWS)  // 128 rows per sample into k2 (16 MB ws)

// f32 -> bf16 bits, RNE
__device__ __forceinline__ short f2bf(float x) {
  unsigned u = __builtin_bit_cast(unsigned, x);
  u += 0x7fffu + ((u >> 16) & 1u);
  return (short)(u >> 16);
}
// packed f32x2 -> bf16x2 (gfx950 v_cvt_pk_bf16_f32, RNE)
__device__ __forceinline__ unsigned pk_bf16(float a, float b) {
  unsigned r;
  asm("v_cvt_pk_bf16_f32 %0, %1, %2" : "=v"(r) : "v"(a), "v"(b));
  return r;
}
// tanh via exp; valid-row preacts norm-bounded; garbage rows write-masked
__device__ __forceinline__ float tanh_fast(float x) {
  float e2 = __expf(2.f * x);
  return (e2 - 1.f) * __builtin_amdgcn_rcpf(e2 + 1.f);
}

// LDS byte address for [row][inner(bytes)] in a [*][256B] bf16 tile; XOR
// swizzle breaks the 256B-row-stride bank alignment for strided ds_read_b128.
__device__ __forceinline__ int swz(int row, int inner) {
  return row * 256 + (inner ^ (((row >> 1) & 7) << 4));
}

// ---- prep (one launch, 161 blocks):
//  b<128   : WmT[n][k] = (k<128 ? (Win@Wc_top)[k][n] : (Win@Wc_bot)[k-128][n])
//  b in [128,160): WcT[n][k] = Wcomp[k][n] bf16
//  b==160  : b1[n] = bin@(Wc_top+Wc_bot)[:,n] + bcomp[n]  (fp32)
__global__ __launch_bounds__(256) void k_prep(
    const float* __restrict__ Win, const float* __restrict__ Wcomp,
    const float* __restrict__ bin, const float* __restrict__ bcomp,
    short* __restrict__ WmT, short* __restrict__ WcT,
    float* __restrict__ b1f) {
  const int b = blockIdx.x, t = threadIdx.x;
  if (b < 128) {
    const int d = b;            // k-index of the folded E-dot
    const int half = t >> 7, n = t & 127;
    float acc = 0.f;
    for (int k = 0; k < 128; ++k)
      acc += Win[d * 128 + k] * Wcomp[(k + 128 * half) * 128 + n];
    WmT[n * 256 + half * 128 + d] = f2bf(acc);
  } else if (b < 160) {
    for (int idx = (b - 128) * 256 + t; idx < 128 * 256; idx += 32 * 256) {
      int n = idx >> 8, k = idx & 255;
      WcT[idx] = f2bf(Wcomp[k * 128 + n]);
    }
  } else {
    if (t < 128) {
      float acc = bcomp[t];
      for (int k = 0; k < 128; ++k)
        acc += bin[k] * (Wcomp[k * 128 + t] + Wcomp[(k + 128) * 128 + t]);
      b1f[t] = acc;
    }
  }
}

// One 16-row tree M-tile: A row i = concat(src[2*(mt_in*16+i)], src[...+1]),
// K=256 against the given B-fragments.
__device__ __forceinline__ void tree_mm(const short* src, int mt_in,
                                        const s16x8 (&wf)[8][2], int lm,
                                        int lh, f32x4& c0, f32x4& c1) {
  s16x8 a[8];
#pragma unroll
  for (int kt = 0; kt < 8; ++kt) {
    int k = kt * 32 + lh * 8;
    int rowbuf = 2 * (mt_in * 16 + lm) + (k >> 7);
    a[kt] = *(const s16x8*)((const char*)src + swz(rowbuf, (k & 127) * 2));
  }
  c0 = (f32x4){0.f, 0.f, 0.f, 0.f};
  c1 = (f32x4){0.f, 0.f, 0.f, 0.f};
#pragma unroll
  for (int kt = 0; kt < 8; ++kt) {
    c0 = __builtin_amdgcn_mfma_f32_16x16x32_bf16(a[kt], wf[kt][0], c0, 0, 0, 0);
    c1 = __builtin_amdgcn_mfma_f32_16x16x32_bf16(a[kt], wf[kt][1], c1, 0, 0, 0);
  }
}

// k1: gather 128 E rows -> lev0' (folded W_in·W_comp) -> lev1..lev3 -> ws.
// ONE weight-fragment array, loaded twice (WmT then WcT) to keep register
// pressure at the R4 level — R7 held both and paid 85 MB of scratch traffic.
__global__ __launch_bounds__(256, 3) void k_subtree(
    const int* __restrict__ ids, const float* __restrict__ emb,
    const short* __restrict__ WmT, const short* __restrict__ WcT,
    const float* __restrict__ b1f, const float* __restrict__ bcomp,
    short* __restrict__ wsbf) {
  __shared__ __align__(16) short ldsB[128 * 128];  // 32 KB: E pairs / pong
  __shared__ __align__(16) short ldsE[64 * 128];   // 16 KB: ping
  const int blk = blockIdx.x, tid = threadIdx.x;
  const int wave = tid >> 6, lane = tid & 63;
  const int lh = lane >> 4, lm = lane & 15;
  const int n0 = wave * 32;
  const int col0 = n0 + 2 * lm;  // lane owns cols col0, col0+1

  // leaf ids
  int idv[16];
#pragma unroll
  for (int it = 0; it < 16; ++it)
    idv[it] = ids[(long)blk * SUB + it * 8 + (tid >> 5)];

  const float2 b1v = *(const float2*)(b1f + col0);
  const float2 bcv = *(const float2*)(bcomp + col0);

  // gather all 128 E rows -> ldsB (bf16, swizzled), single phase
#pragma unroll
  for (int it = 0; it < 16; ++it) {
    int r = it * 8 + (tid >> 5);
    const float4 v = ((const float4*)(emb + (long)idv[it] * DD))[tid & 31];
    uint2 pv;
    pv.x = pk_bf16(v.x, v.y);
    pv.y = pk_bf16(v.z, v.w);
    *(uint2*)((char*)ldsB + swz(r, (tid & 31) * 8)) = pv;
  }

  // weight fragments for lev0' (folded M); idv now dead
  s16x8 wf[8][2];
#pragma unroll
  for (int kt = 0; kt < 8; ++kt)
#pragma unroll
    for (int nt = 0; nt < 2; ++nt)
      wf[kt][nt] = *(const s16x8*)(WmT + (col0 + nt) * 256 + kt * 32 + lh * 8);
  __syncthreads();

  // lev0': E pairs (128 rows) x M -> ldsE rows 0-63 (tanh, folded bias)
#pragma unroll 1
  for (int mt = 0; mt < 4; ++mt) {
    f32x4 c0, c1;
    tree_mm(ldsB, mt, wf, lm, lh, c0, c1);
#pragma unroll
    for (int r = 0; r < 4; ++r) {
      int row = mt * 16 + lh * 4 + r;
      *(unsigned*)((char*)ldsE + swz(row, col0 * 2)) =
          pk_bf16(tanh_fast(c0[r] + b1v.x), tanh_fast(c1[r] + b1v.y));
    }
  }

  // reload fragments from WcT (WAR on wf: issues after last wfm MFMA;
  // L2-hot, latency hides under the barrier)
#pragma unroll
  for (int kt = 0; kt < 8; ++kt)
#pragma unroll
    for (int nt = 0; nt < 2; ++nt)
      wf[kt][nt] = *(const s16x8*)(WcT + (col0 + nt) * 256 + kt * 32 + lh * 8);
  __syncthreads();

  // lev1: ldsE(64) -> ldsB rows 0-31
#pragma unroll 1
  for (int mt = 0; mt < 2; ++mt) {
    f32x4 c0, c1;
    tree_mm(ldsE, mt, wf, lm, lh, c0, c1);
#pragma unroll
    for (int r = 0; r < 4; ++r) {
      int row = mt * 16 + lh * 4 + r;
      *(unsigned*)((char*)ldsB + swz(row, col0 * 2)) =
          pk_bf16(tanh_fast(c0[r] + bcv.x), tanh_fast(c1[r] + bcv.y));
    }
  }
  __syncthreads();

  // lev2: ldsB(32) -> ldsE rows 0-15 (all valid)
  {
    f32x4 c0, c1;
    tree_mm(ldsB, 0, wf, lm, lh, c0, c1);
#pragma unroll
    for (int r = 0; r < 4; ++r) {
      int row = lh * 4 + r;
      *(unsigned*)((char*)ldsE + swz(row, col0 * 2)) =
          pk_bf16(tanh_fast(c0[r] + bcv.x), tanh_fast(c1[r] + bcv.y));
    }
  }
  __syncthreads();

  // lev3: ldsE rows 0-15 valid (16-31 stale lev0', finite) -> global, 8 rows
  // D rows 0-7 use A pair-rows 0-15 (valid only); garbage reaches rows >=8.
  {
    f32x4 c0, c1;
    tree_mm(ldsE, 0, wf, lm, lh, c0, c1);
#pragma unroll
    for (int r = 0; r < 4; ++r) {
      int row = lh * 4 + r;
      if (row < K1ROWS)
        *(unsigned*)(wsbf + ((long)blk * K1ROWS + row) * HH + col0) =
            pk_bf16(tanh_fast(c0[r] + bcv.x), tanh_fast(c1[r] + bcv.y));
    }
  }
}

// ---- k2: per-sample 128 rows -> root -> classifier (MFMA) ----
__global__ __launch_bounds__(256, 2) void k_tree2(
    const short* __restrict__ wsbf, const short* __restrict__ WcT,
    const float* __restrict__ bcomp, const float* __restrict__ Wcls,
    const float* __restrict__ bcls, float* __restrict__ out) {
  __shared__ __align__(16) short srcL[128 * 128];  // 32 KB
  __shared__ __align__(16) short dstS[64 * 128];   // 16 KB
  __shared__ float rootL[128];
  const int b = blockIdx.x, tid = threadIdx.x;
  const int wave = tid >> 6, lane = tid & 63;
  const int lh = lane >> 4, lm = lane & 15;
  const int n0 = wave * 32;
  const int col0 = n0 + 2 * lm;

  s16x8 wfc[8][2];
#pragma unroll
  for (int kt = 0; kt < 8; ++kt)
#pragma unroll
    for (int nt = 0; nt < 2; ++nt)
      wfc[kt][nt] = *(const s16x8*)(WcT + (col0 + nt) * 256 + kt * 32 + lh * 8);
  const float2 bcv = *(const float2*)(bcomp + col0);

  // load 128 rows of bf16 (16 B per lane, coalesced) -> srcL swizzled
#pragma unroll
  for (int it = 0; it < 8; ++it) {
    int row = it * 16 + (tid >> 4);
    s16x8 v = *(const s16x8*)(wsbf + ((long)b * K2ROWS + row) * HH + (tid & 15) * 8);
    *(s16x8*)((char*)srcL + swz(row, (tid & 15) * 16)) = v;
  }
  __syncthreads();

  const short* src = srcL;
  short* dst = dstS;
  // levels: 128->64->32->16->8->4->2->1 ; mtiles 4,2,1,1,1,1,1
  const int mtiles[7] = {4, 2, 1, 1, 1, 1, 1};
  const int rlim[7] = {64, 32, 16, 8, 4, 2, 1};
#pragma unroll 1
  for (int lev = 0; lev < 7; ++lev) {
    int nmt = mtiles[lev], rl = rlim[lev];
#pragma unroll 1
    for (int mt = 0; mt < nmt; ++mt) {
      f32x4 c0, c1;
      tree_mm(src, mt, wfc, lm, lh, c0, c1);
      if (lev == 6) {
        if (lh == 0) {
          rootL[col0] = tanh_fast(c0[0] + bcv.x);
          rootL[col0 + 1] = tanh_fast(c1[0] + bcv.y);
        }
      } else {
#pragma unroll
        for (int r = 0; r < 4; ++r) {
          int row = mt * 16 + lh * 4 + r;
          if (row < rl)
            *(unsigned*)((char*)dst + swz(row, col0 * 2)) =
                pk_bf16(tanh_fast(c0[r] + bcv.x), tanh_fast(c1[r] + bcv.y));
        }
      }
    }
    __syncthreads();
    const short* t = src;
    src = dst;
    dst = (short*)t;
  }

  // classifier: wave 0; lane -> (class = lane&1, k-chunk = lane>>1)
  if (wave == 0) {
    int c = lane & 1, kb = lane >> 1;
    float p = 0.f;
#pragma unroll
    for (int j = 0; j < 4; ++j) {
      int k = kb + 32 * j;
      p += rootL[k] * Wcls[k * 2 + c];
    }
#pragma unroll
    for (int m = 2; m <= 32; m <<= 1) p += __shfl_xor(p, m, 64);
    if (lane < 2) out[b * 2 + lane] = p + bcls[lane];
  }
}

extern "C" void kernel_launch(void* const* d_in, const int* in_sizes, int n_in,
                              void* d_out, int out_size, void* d_ws, size_t ws_size,
                              hipStream_t stream) {
  const int*   ids   = (const int*)d_in[0];
  const float* emb   = (const float*)d_in[1];
  const float* Win   = (const float*)d_in[2];
  const float* bin   = (const float*)d_in[3];
  const float* Wcomp = (const float*)d_in[4];
  const float* bcomp = (const float*)d_in[5];
  const float* Wcls  = (const float*)d_in[6];
  const float* bcls  = (const float*)d_in[7];
  char* wsb = (char*)d_ws;
  // layout: [wsbf 16 MB][WcT 64 KB][WmT 128 KB][b1 512 B]
  short* wsbf = (short*)wsb;
  const size_t WSBF_BYTES = (size_t)BB * NSUB * K1ROWS * HH * 2;  // 16 MB
  short* WcT = (short*)(wsb + WSBF_BYTES);
  short* WmT = (short*)(wsb + WSBF_BYTES + (64 << 10));
  float* b1f = (float*)(wsb + WSBF_BYTES + (192 << 10));
  float* out = (float*)d_out;

  hipLaunchKernelGGL(k_prep, dim3(161), dim3(256), 0, stream,
                     Win, Wcomp, bin, bcomp, WmT, WcT, b1f);
  hipLaunchKernelGGL(k_subtree, dim3(NBLK), dim3(256), 0, stream,
                     ids, emb, WmT, WcT, b1f, bcomp, wsbf);
  hipLaunchKernelGGL(k_tree2, dim3(BB), dim3(256), 0, stream,
                     wsbf, WcT, bcomp, Wcls, bcls, out);
}